// Round 4
// baseline (794.998 us; speedup 1.0000x reference)
//
#include <hip/hip_runtime.h>
#include <hip/hip_bf16.h>

#define BB 4
#define SS 1024
#define FF 1024
#define HH 16
#define DH 64

typedef short bf16x8 __attribute__((ext_vector_type(8)));
typedef float f32x4 __attribute__((ext_vector_type(4)));

__device__ __forceinline__ float b2f(unsigned short u) {
    union { unsigned int i; float f; } x; x.i = ((unsigned int)u) << 16; return x.f;
}
__device__ __forceinline__ unsigned short f2b(float f) {
    unsigned int x = __float_as_uint(f);
    unsigned int r = (x + 0x7fffu + ((x >> 16) & 1u)) >> 16;
    return (unsigned short)r;
}

// ---------------- fp32 -> bf16 conversion ----------------
__global__ void cvt_k(const float* __restrict__ in, unsigned short* __restrict__ out, int n) {
    int i = (blockIdx.x * blockDim.x + threadIdx.x) * 4;
    if (i < n) {
        float4 v = *(const float4*)(in + i);
        ushort4 o;
        o.x = f2b(v.x); o.y = f2b(v.y); o.z = f2b(v.z); o.w = f2b(v.w);
        *(ushort4*)(out + i) = o;
    }
}

// ---------------- 128x128 MFMA GEMM: C = A @ W + bias ----------------
// A: [4096][1024] row-major bf16. W: [k][n] row-major bf16 (transposed in staging).
// bias: fp32. mode 0: fp32 out[row*F+col]; mode 1: bf16 qkv scatter + scale
#define LDK 40   // 32 + 8 pad (stride in elems; 80 B, 16B-aligned)
__global__ __launch_bounds__(256, 2) void gemm_k(
    const unsigned short* __restrict__ A, const unsigned short* __restrict__ W,
    const float* __restrict__ bias,
    unsigned short* __restrict__ o16, float* __restrict__ o32, float scale, int mode)
{
    __shared__ __attribute__((aligned(16))) unsigned short lA[128 * LDK];
    __shared__ __attribute__((aligned(16))) unsigned short lB[128 * LDK];

    int tid = threadIdx.x;
    int wave = tid >> 6, lane = tid & 63, quad = lane >> 4, l16 = lane & 15;
    int wm = (wave & 1) * 64, wn = (wave >> 1) * 64;
    int mbase = blockIdx.x * 128, nbase = blockIdx.y * 128;

    f32x4 acc[4][4];
    #pragma unroll
    for (int i = 0; i < 4; i++)
        #pragma unroll
        for (int j = 0; j < 4; j++) acc[i][j] = (f32x4){0.f, 0.f, 0.f, 0.f};

    for (int k0 = 0; k0 < FF; k0 += 32) {
        // A tile: 128 m-rows x 32 k
        #pragma unroll
        for (int c = tid; c < 512; c += 256) {
            int row = c >> 2, col = (c & 3) * 8;
            *(uint4*)(&lA[row * LDK + col]) = *(const uint4*)(&A[(size_t)(mbase + row) * FF + k0 + col]);
        }
        // B tile: 32 k-rows x 128 n, transposed into lB[n][k]
        #pragma unroll
        for (int c = tid; c < 512; c += 256) {
            int kk = c >> 4;             // 0..31
            int nn = (c & 15) * 8;       // 0..120
            uint4 u = *(const uint4*)(&W[(size_t)(k0 + kk) * FF + nbase + nn]);
            const unsigned short* us = (const unsigned short*)&u;
            #pragma unroll
            for (int j = 0; j < 8; j++) lB[(nn + j) * LDK + kk] = us[j];
        }
        __syncthreads();
        bf16x8 af[4], bfr[4];
        #pragma unroll
        for (int i = 0; i < 4; i++)
            af[i] = *(const bf16x8*)(&lA[(wm + i * 16 + l16) * LDK + quad * 8]);
        #pragma unroll
        for (int i = 0; i < 4; i++)
            bfr[i] = *(const bf16x8*)(&lB[(wn + i * 16 + l16) * LDK + quad * 8]);
        #pragma unroll
        for (int mi = 0; mi < 4; mi++)
            #pragma unroll
            for (int ni = 0; ni < 4; ni++)
                acc[mi][ni] = __builtin_amdgcn_mfma_f32_16x16x32_bf16(af[mi], bfr[ni], acc[mi][ni], 0, 0, 0);
        __syncthreads();
    }
    // epilogue
    #pragma unroll
    for (int mi = 0; mi < 4; mi++) {
        #pragma unroll
        for (int ni = 0; ni < 4; ni++) {
            int col = nbase + wn + ni * 16 + l16;
            float bv = bias[col];
            #pragma unroll
            for (int r = 0; r < 4; r++) {
                int row = mbase + wm + mi * 16 + quad * 4 + r;
                float v = (acc[mi][ni][r] + bv) * scale;
                if (mode == 1) {
                    int b_ = row >> 10, i = row & 1023;
                    int h = i >> 6, s_ = ((i & 63) << 4) + (col >> 6), d = col & 63;
                    o16[(((size_t)(b_ * HH + h)) * SS + s_) * DH + d] = f2b(v);
                } else {
                    o32[(size_t)row * FF + col] = v;
                }
            }
        }
    }
}

// ---------------- per-row stats of masked str rows (fp32 in) ----------------
__global__ void rowstats_k(const float* __restrict__ str,
                           float* __restrict__ rmax, float* __restrict__ rinv) {
    int row = blockIdx.x * 4 + (threadIdx.x >> 6);   // [0, B*H*S)
    int lane = threadIdx.x & 63;
    int r = row & (SS - 1);
    const float* p = str + (size_t)row * SS;
    float vals[16];
    float mx = -1e30f;
    #pragma unroll
    for (int i = 0; i < 4; i++) {
        int k0 = i * 256 + lane * 4;
        float4 u = *(const float4*)(&p[k0]);
        float uv[4] = {u.x, u.y, u.z, u.w};
        #pragma unroll
        for (int j = 0; j < 4; j++) {
            float v = (k0 + j <= r) ? uv[j] : -1e30f;
            vals[i * 4 + j] = v;
            mx = fmaxf(mx, v);
        }
    }
    #pragma unroll
    for (int d = 1; d < 64; d <<= 1) mx = fmaxf(mx, __shfl_xor(mx, d));
    float sum = 0.f;
    #pragma unroll
    for (int i = 0; i < 16; i++) sum += __expf(fminf(vals[i] - mx, 0.f));
    #pragma unroll
    for (int d = 1; d < 64; d <<= 1) sum += __shfl_xor(sum, d);
    if (lane == 0) { rmax[row] = mx; rinv[row] = 1.0f / sum; }
}

// ---------------- fused attention ----------------
// Q prescaled by 1/64. scores = QK^T + sm; full-row softmax; O = P@V.
#define LDT 72   // 64 + 8 pad
__global__ __launch_bounds__(256, 2) void attn_k(
    const unsigned short* __restrict__ Q, const unsigned short* __restrict__ Kt,
    const unsigned short* __restrict__ V, const float* __restrict__ str,
    const float* __restrict__ rmax, const float* __restrict__ rinv,
    unsigned short* __restrict__ ctx)
{
    int bh = blockIdx.y;
    int b_ = bh >> 4, h = bh & 15;
    int qbase = blockIdx.x * 64;
    int tid = threadIdx.x;
    int wave = tid >> 6, lane = tid & 63, quad = lane >> 4, l16 = lane & 15;

    __shared__ __attribute__((aligned(16))) unsigned short lQ[64 * LDT];
    __shared__ __attribute__((aligned(16))) unsigned short lK[64 * LDT];
    __shared__ __attribute__((aligned(16))) unsigned short lVT[64 * LDT];
    __shared__ __attribute__((aligned(16))) unsigned short lP[4][16 * LDT];
    __shared__ float lrm[64], lri[64];

    const size_t slab = (size_t)bh * SS * DH;
    #pragma unroll
    for (int c = tid; c < 512; c += 256) {
        int row = c >> 3, col = (c & 7) * 8;
        *(uint4*)(&lQ[row * LDT + col]) = *(const uint4*)(&Q[slab + (size_t)(qbase + row) * DH + col]);
    }
    if (tid < 64) {
        lrm[tid] = rmax[bh * SS + qbase + tid];
        lri[tid] = rinv[bh * SS + qbase + tid];
    }

    float m_st[4], l_st[4];
    f32x4 Oacc[4];
    #pragma unroll
    for (int r = 0; r < 4; r++) { m_st[r] = -1e30f; l_st[r] = 0.f; }
    #pragma unroll
    for (int ni = 0; ni < 4; ni++) Oacc[ni] = (f32x4){0.f, 0.f, 0.f, 0.f};

    const size_t strbase = (size_t)bh * SS * SS;

    for (int tt = 0; tt < 16; tt++) {
        int tbase = tt * 64;
        __syncthreads();   // protect lK/lVT (prev iter) + lQ/lrm on first iter
        #pragma unroll
        for (int c = tid; c < 512; c += 256) {
            int row = c >> 3, col = (c & 7) * 8;
            *(uint4*)(&lK[row * LDT + col]) = *(const uint4*)(&Kt[slab + (size_t)(tbase + row) * DH + col]);
        }
        #pragma unroll
        for (int c = tid; c < 512; c += 256) {
            int row = c >> 3, col = (c & 7) * 8;
            uint4 u = *(const uint4*)(&V[slab + (size_t)(tbase + row) * DH + col]);
            const unsigned short* us = (const unsigned short*)&u;
            #pragma unroll
            for (int j = 0; j < 8; j++) lVT[(col + j) * LDT + row] = us[j];
        }
        __syncthreads();

        // S = Q @ K^T  (16x64 per wave)
        f32x4 sa[4];
        #pragma unroll
        for (int ni = 0; ni < 4; ni++) sa[ni] = (f32x4){0.f, 0.f, 0.f, 0.f};
        #pragma unroll
        for (int ks = 0; ks < 2; ks++) {
            bf16x8 a = *(const bf16x8*)(&lQ[(wave * 16 + l16) * LDT + ks * 32 + quad * 8]);
            #pragma unroll
            for (int ni = 0; ni < 4; ni++) {
                bf16x8 b = *(const bf16x8*)(&lK[(ni * 16 + l16) * LDT + ks * 32 + quad * 8]);
                sa[ni] = __builtin_amdgcn_mfma_f32_16x16x32_bf16(a, b, sa[ni], 0, 0, 0);
            }
        }

        // scores = S + sm ; online softmax
        float p[4][4], tm[4];
        #pragma unroll
        for (int r = 0; r < 4; r++) tm[r] = -1e30f;
        #pragma unroll
        for (int ni = 0; ni < 4; ni++) {
            int t_abs = tbase + ni * 16 + l16;
            #pragma unroll
            for (int r = 0; r < 4; r++) {
                int q_loc = wave * 16 + quad * 4 + r;
                int q_abs = qbase + q_loc;
                float smv = 0.f;
                if (t_abs <= q_abs) {
                    float sv = str[strbase + (size_t)q_abs * SS + t_abs];
                    smv = __expf(fminf(sv - lrm[q_loc], 0.f)) * lri[q_loc];
                }
                p[ni][r] = sa[ni][r] + smv;
                tm[r] = fmaxf(tm[r], p[ni][r]);
            }
        }
        #pragma unroll
        for (int r = 0; r < 4; r++) {
            float v = tm[r];
            v = fmaxf(v, __shfl_xor(v, 1));
            v = fmaxf(v, __shfl_xor(v, 2));
            v = fmaxf(v, __shfl_xor(v, 4));
            v = fmaxf(v, __shfl_xor(v, 8));
            tm[r] = v;
        }
        float alpha[4], rs[4];
        #pragma unroll
        for (int r = 0; r < 4; r++) {
            float mn = fmaxf(m_st[r], tm[r]);
            alpha[r] = __expf(fminf(m_st[r] - mn, 0.f));
            m_st[r] = mn;
            rs[r] = 0.f;
        }
        #pragma unroll
        for (int ni = 0; ni < 4; ni++)
            #pragma unroll
            for (int r = 0; r < 4; r++) {
                p[ni][r] = __expf(fminf(p[ni][r] - m_st[r], 0.f));
                rs[r] += p[ni][r];
            }
        #pragma unroll
        for (int r = 0; r < 4; r++) {
            float v = rs[r];
            v += __shfl_xor(v, 1); v += __shfl_xor(v, 2);
            v += __shfl_xor(v, 4); v += __shfl_xor(v, 8);
            l_st[r] = l_st[r] * alpha[r] + v;
        }
        #pragma unroll
        for (int ni = 0; ni < 4; ni++)
            #pragma unroll
            for (int r = 0; r < 4; r++) Oacc[ni][r] *= alpha[r];

        // P -> LDS (C-layout write, A-layout read)
        unsigned short* lPw = lP[wave];
        #pragma unroll
        for (int ni = 0; ni < 4; ni++)
            #pragma unroll
            for (int r = 0; r < 4; r++)
                lPw[(quad * 4 + r) * LDT + ni * 16 + l16] = f2b(p[ni][r]);
        __syncthreads();

        // O += P @ V
        #pragma unroll
        for (int ks = 0; ks < 2; ks++) {
            bf16x8 a = *(const bf16x8*)(&lPw[l16 * LDT + ks * 32 + quad * 8]);
            #pragma unroll
            for (int ni = 0; ni < 4; ni++) {
                bf16x8 b = *(const bf16x8*)(&lVT[(ni * 16 + l16) * LDT + ks * 32 + quad * 8]);
                Oacc[ni] = __builtin_amdgcn_mfma_f32_16x16x32_bf16(a, b, Oacc[ni], 0, 0, 0);
            }
        }
    }

    // epilogue: ctx[b][s][h*64+d]
    #pragma unroll
    for (int ni = 0; ni < 4; ni++) {
        int d = ni * 16 + l16;
        #pragma unroll
        for (int r = 0; r < 4; r++) {
            int s_abs = qbase + wave * 16 + quad * 4 + r;
            float v = Oacc[ni][r] / l_st[r];
            ctx[((size_t)b_ * SS + s_abs) * FF + h * 64 + d] = f2b(v);
        }
    }
}

extern "C" void kernel_launch(void* const* d_in, const int* in_sizes, int n_in,
                              void* d_out, int out_size, void* d_ws, size_t ws_size,
                              hipStream_t stream) {
    const float* x   = (const float*)d_in[0];
    const float* str = (const float*)d_in[1];
    const float* Wq  = (const float*)d_in[3];
    const float* bq  = (const float*)d_in[4];
    const float* Wk  = (const float*)d_in[5];
    const float* bk  = (const float*)d_in[6];
    const float* Wv  = (const float*)d_in[7];
    const float* bv  = (const float*)d_in[8];
    const float* Wo  = (const float*)d_in[9];
    const float* bo  = (const float*)d_in[10];

    // workspace layout (48.5 MB):
    //   xb   : 8 MB   (4M bf16)        [0, 8)
    //   Wb   : 8 MB   (4 x 1M bf16)    [8, 16)
    //   QKV  : 24 MB  (3 x 4M bf16)    [16, 40)
    //   ctx  : 8 MB   (4M bf16)        [40, 48)
    //   rmax : 256 KB (64K fp32)       [48, 48.25)
    //   rinv : 256 KB (64K fp32)       [48.25, 48.5)
    char* ws = (char*)d_ws;
    const size_t MB = 1024ull * 1024;
    unsigned short* xb  = (unsigned short*)ws;
    unsigned short* Wb  = (unsigned short*)(ws + 8 * MB);
    unsigned short* QKV = (unsigned short*)(ws + 16 * MB);
    unsigned short* ctx = (unsigned short*)(ws + 40 * MB);
    float* rmax = (float*)(ws + 48 * MB);
    float* rinv = (float*)(ws + 48 * MB + 256 * 1024);

    const size_t QN = (size_t)BB * SS * FF;   // 4M elems
    const size_t WN = (size_t)FF * FF;        // 1M elems

    cvt_k<<<4096, 256, 0, stream>>>(x,  xb,           (int)QN);
    cvt_k<<<1024, 256, 0, stream>>>(Wq, Wb,           (int)WN);
    cvt_k<<<1024, 256, 0, stream>>>(Wk, Wb + WN,      (int)WN);
    cvt_k<<<1024, 256, 0, stream>>>(Wv, Wb + 2 * WN,  (int)WN);
    cvt_k<<<1024, 256, 0, stream>>>(Wo, Wb + 3 * WN,  (int)WN);

    gemm_k<<<dim3(32, 8), 256, 0, stream>>>(xb, Wb,          bq, QKV,          nullptr, 0.015625f, 1);
    gemm_k<<<dim3(32, 8), 256, 0, stream>>>(xb, Wb + WN,     bk, QKV + QN,     nullptr, 1.0f,      1);
    gemm_k<<<dim3(32, 8), 256, 0, stream>>>(xb, Wb + 2 * WN, bv, QKV + 2 * QN, nullptr, 1.0f,      1);
    rowstats_k<<<16384, 256, 0, stream>>>(str, rmax, rinv);
    attn_k<<<dim3(16, 64), 256, 0, stream>>>(QKV, QKV + QN, QKV + 2 * QN, str, rmax, rinv, ctx);
    gemm_k<<<dim3(32, 8), 256, 0, stream>>>(ctx, Wb + 3 * WN, bo, nullptr, (float*)d_out, 1.0f, 0);
}